// Round 8
// baseline (27610.880 us; speedup 1.0000x reference)
//
#include <hip/hip_runtime.h>

// Problem constants
#define BATCH   16
#define NPTS    32768
#define NPOINT  2048
#define C_FEAT  128

#define NTH     1024
#define PPT     32            // points per thread
#define NW      16            // waves per block

// ===========================================================================
// Round 8: lazy FPS. Exact-trajectory invariants:
//  - distance pipeline is r7's verified FMA form: fmaf(dz,dz,fmaf(dy,dy,dx*dx))
//  - a chunk is skipped ONLY when bboxdist^2*0.999 > max(dmin[chunk]) -- then
//    min(dmin,d)==dmin for every member (margin >> 4-ulp rounding), so all
//    dmin[] bits match the reference's at every step.
//  - argmax = (max of per-chunk maxima) then min ORIGINAL index among
//    dmin==M (packed-key atomicMin) == np.argmax first-occurrence, and is
//    independent of the internal spatial permutation (so the unordered
//    scatter can't affect output, only perf).
// ws layout: [fps_idx 128KB @0][pos0 @128KB][x_t @2MB][y_t @4MB][z_t @6MB]
//            [oidx_t @8MB]  (10 MB total)
// ===========================================================================

__device__ inline unsigned part4(unsigned v) {  // spread 4 bits to every 3rd
  return (v & 1u) | ((v & 2u) << 2) | ((v & 4u) << 4) | ((v & 8u) << 6);
}
__device__ inline int cell_of(float x, float y, float z) {
  int qx = min(15, max(0, (int)((x + 5.0f) * 1.6f)));
  int qy = min(15, max(0, (int)((y + 5.0f) * 1.6f)));
  int qz = min(15, max(0, (int)((z + 5.0f) * 1.6f)));
  return (int)(part4((unsigned)qx) | (part4((unsigned)qy) << 1) |
               (part4((unsigned)qz) << 2));          // 12-bit Morton
}

// ---------------------------------------------------------------------------
// Spatial counting sort (one block per batch): Morton-4/4/4 cells, LDS
// histogram + block scan + scatter into chunk-transposed layout:
// sorted position p -> t_idx = (p&31)*1024 + (p>>5), so thread j's chunk
// (sorted positions j*32..j*32+31) is read coalesced at [k*1024 + j].
// ---------------------------------------------------------------------------
__global__ __launch_bounds__(NTH) void sort_kernel(
    const float* __restrict__ xyz, float* __restrict__ x_t,
    float* __restrict__ y_t, float* __restrict__ z_t,
    int* __restrict__ oidx_t, int* __restrict__ pos0) {
  const int b = blockIdx.x, t = threadIdx.x, lane = t & 63;
  const float* __restrict__ base = xyz + (size_t)b * NPTS * 3;
  __shared__ unsigned bins[4096];
  __shared__ unsigned wsum[NW];

  for (int i = t; i < 4096; i += NTH) bins[i] = 0u;
  __syncthreads();

  // histogram
  for (int k = 0; k < PPT; ++k) {
    const int p = k * NTH + t;
    const float x = base[p * 3], y = base[p * 3 + 1], z = base[p * 3 + 2];
    atomicAdd(&bins[cell_of(x, y, z)], 1u);
  }
  __syncthreads();

  // exclusive scan over 4096 bins (thread owns bins[4t..4t+4))
  unsigned c0 = bins[4 * t], c1 = bins[4 * t + 1], c2 = bins[4 * t + 2],
           c3 = bins[4 * t + 3];
  const unsigned mysum = c0 + c1 + c2 + c3;
  unsigned acc = mysum;                       // wave-inclusive scan
#pragma unroll
  for (int d = 1; d < 64; d <<= 1) {
    unsigned n = __shfl_up(acc, d);
    if (lane >= d) acc += n;
  }
  if (lane == 63) wsum[t >> 6] = acc;
  __syncthreads();
  unsigned woff = 0;
  for (int w = 0; w < (t >> 6); ++w) woff += wsum[w];
  unsigned run = woff + acc - mysum;          // block-exclusive for this thread
  bins[4 * t] = run; run += c0;
  bins[4 * t + 1] = run; run += c1;
  bins[4 * t + 2] = run; run += c2;
  bins[4 * t + 3] = run;
  __syncthreads();

  // scatter
  for (int k = 0; k < PPT; ++k) {
    const int p = k * NTH + t;
    const float x = base[p * 3], y = base[p * 3 + 1], z = base[p * 3 + 2];
    const unsigned pos = atomicAdd(&bins[cell_of(x, y, z)], 1u);
    const int tix = (int)(((pos & 31u) << 10) | (pos >> 5));
    const size_t o = (size_t)b * NPTS + tix;
    x_t[o] = x; y_t[o] = y; z_t[o] = z; oidx_t[o] = p;
    if (p == 0) pos0[b] = (int)pos;
  }
}

// ---------------------------------------------------------------------------
// Lazy FPS (one block per batch).
// ---------------------------------------------------------------------------
__global__ __launch_bounds__(NTH) void fps_kernel(
    const float* __restrict__ x_t, const float* __restrict__ y_t,
    const float* __restrict__ z_t, const int* __restrict__ oidx_t,
    const int* __restrict__ pos0, int* __restrict__ fps_idx) {
  const int b = blockIdx.x, t = threadIdx.x;
  const int lane = t & 63, w = t >> 6;
  const float* __restrict__ X = x_t + (size_t)b * NPTS;
  const float* __restrict__ Y = y_t + (size_t)b * NPTS;
  const float* __restrict__ Z = z_t + (size_t)b * NPTS;
  const int* __restrict__ OI = oidx_t + (size_t)b * NPTS;

  __shared__ float s_wmax[NW];
  __shared__ int   s_gkey[2];

  // chunk bbox + dmin init
  float dmin[PPT];
  float bxl = 1e30f, bxh = -1e30f, byl = 1e30f, byh = -1e30f,
        bzl = 1e30f, bzh = -1e30f;
#pragma unroll
  for (int k = 0; k < PPT; ++k) {
    const int a = (k << 10) + t;
    const float x = X[a], y = Y[a], z = Z[a];
    bxl = fminf(bxl, x); bxh = fmaxf(bxh, x);
    byl = fminf(byl, y); byh = fmaxf(byh, y);
    bzl = fminf(bzl, z); bzh = fmaxf(bzh, z);
    dmin[k] = 1e10f;
  }
  float chunkmax = 1e10f;
  int far_orig = 0;
  int spos = pos0[b];
  if (t == 0) { s_gkey[0] = 0x7fffffff; s_gkey[1] = 0x7fffffff; }
  __syncthreads();

  for (int s = 0; s < NPOINT; ++s) {
    if (t == 0) fps_idx[b * NPOINT + s] = far_orig;

    const int ca = ((spos & 31) << 10) | (spos >> 5);
    const float cx = X[ca], cy = Y[ca], cz = Z[ca];   // broadcast loads

    // prune: min possible dist^2 from centroid to chunk bbox
    const float ddx = fmaxf(fmaxf(bxl - cx, cx - bxh), 0.0f);
    const float ddy = fmaxf(fmaxf(byl - cy, cy - byh), 0.0f);
    const float ddz = fmaxf(fmaxf(bzl - cz, cz - bzh), 0.0f);
    const float r2 = ddx * ddx + ddy * ddy + ddz * ddz;

    if (!(r2 * 0.999f > chunkmax)) {   // must update (margin >> rounding err)
      float vm = -1.0f;
#pragma unroll
      for (int k = 0; k < PPT; ++k) {
        const int a = (k << 10) + t;
        const float dx = X[a] - cx;
        const float dy = Y[a] - cy;
        const float dz = Z[a] - cz;
        // EXACT reference pipeline (verified round 7):
        const float d = __builtin_fmaf(dz, dz, __builtin_fmaf(dy, dy, dx * dx));
        const float nd = fminf(dmin[k], d);
        dmin[k] = nd;
        vm = fmaxf(vm, nd);
      }
      chunkmax = vm;
    }

    // pass 1: block max of per-chunk maxima
    float v = chunkmax;
#pragma unroll
    for (int off = 32; off > 0; off >>= 1) v = fmaxf(v, __shfl_xor(v, off));
    if (lane == 0) s_wmax[w] = v;
    __syncthreads();                                  // barrier 1
    float M = s_wmax[lane & 15];
#pragma unroll
    for (int off = 8; off > 0; off >>= 1) M = fmaxf(M, __shfl_xor(M, off));

    if (t == 0) s_gkey[(s + 1) & 1] = 0x7fffffff;     // reset ping-pong slot

    // pass 2: min (orig_idx, sorted_pos) key among dmin == M
    if (chunkmax == M) {
#pragma unroll
      for (int k = 0; k < PPT; ++k) {
        if (dmin[k] == M) {
          const int oi = OI[(k << 10) + t];
          const int p = (t << 5) | k;                 // sorted position
          atomicMin(&s_gkey[s & 1], (oi << 15) | p);
        }
      }
    }
    __syncthreads();                                  // barrier 2
    const int key = s_gkey[s & 1];
    far_orig = key >> 15;
    spos = key & 32767;
  }
}

// ---------------------------------------------------------------------------
// Gather: [B][NPOINT][3] then [B][NPOINT][128], concatenated flat.
// ---------------------------------------------------------------------------
__global__ __launch_bounds__(256) void gather_kernel(
    const float* __restrict__ xyz, const float* __restrict__ feat,
    const int* __restrict__ fps_idx, float* __restrict__ out) {
  const int lane = threadIdx.x & 31;
  const int sub  = threadIdx.x >> 5;
  const int row  = blockIdx.x * 8 + sub;
  const int b    = row >> 11;
  const int src  = fps_idx[row];

  const float4* __restrict__ f =
      reinterpret_cast<const float4*>(feat + ((size_t)b * NPTS + src) * C_FEAT);
  float4* __restrict__ o =
      reinterpret_cast<float4*>(out + (size_t)BATCH * NPOINT * 3 +
                                (size_t)row * C_FEAT);
  o[lane] = f[lane];
  if (lane < 3) {
    out[(size_t)row * 3 + lane] = xyz[((size_t)b * NPTS + src) * 3 + lane];
  }
}

extern "C" void kernel_launch(void* const* d_in, const int* in_sizes, int n_in,
                              void* d_out, int out_size, void* d_ws, size_t ws_size,
                              hipStream_t stream) {
  (void)in_sizes; (void)n_in; (void)out_size; (void)ws_size;
  const float* xyz  = (const float*)d_in[0];
  const float* feat = (const float*)d_in[1];
  float* out = (float*)d_out;

  char* ws = (char*)d_ws;
  int*   fps_idx = (int*)ws;                         // 128 KB
  int*   pos0    = (int*)(ws + (1u << 17));          // @128KB
  float* x_t     = (float*)(ws + (2u << 20));        // 2 MB each
  float* y_t     = (float*)(ws + (4u << 20));
  float* z_t     = (float*)(ws + (6u << 20));
  int*   oidx_t  = (int*)(ws + (8u << 20));          // ends @10MB

  sort_kernel<<<BATCH, NTH, 0, stream>>>(xyz, x_t, y_t, z_t, oidx_t, pos0);
  fps_kernel<<<BATCH, NTH, 0, stream>>>(x_t, y_t, z_t, oidx_t, pos0, fps_idx);
  gather_kernel<<<(BATCH * NPOINT) / 8, 256, 0, stream>>>(xyz, feat, fps_idx, out);
}